// Round 2
// baseline (194.950 us; speedup 1.0000x reference)
//
#include <hip/hip_runtime.h>
#include <float.h>
#include <math.h>

#define KP 500000
#define KN 25000
#define KK 30
#define KD 128

// ---------------------------------------------------------------------------
// Fully fused GAT layer: one 64-lane wave per output row.
//   For node n (row r = n+1), neighbors k=0..29 with pair index ik = scope[n][k]
//   (0 = padding; padding is trailing since scope pads tail positions).
//   e_k = softplus( zf[ik-1]·W[0:128] + zo[ik-1]·W[128:256] )   (lazy, per ref)
//   alpha = softmax over valid k;  out[r] = sum_k alpha_k * zo[ik-1]
//
// Each lane owns 2 columns (col = lane*2). Per k:
//   - branchless gather (padding clamps to row 0, which stays L1-hot)
//   - per-lane partial dot, then 6-round __shfl_xor butterfly -> e_k on all lanes
//   - zo slice kept in registers (zr[k]) for the weighted sum -> no re-read
// Softmax is computed redundantly per lane (no cross-lane ops needed since
// every lane holds all 30 e_k after the allreduce).
// ---------------------------------------------------------------------------
__global__ __launch_bounds__(256, 2) void fused_gat_kernel(
    const float* __restrict__ zf, const float* __restrict__ zo,
    const int* __restrict__ scope, const float* __restrict__ W,
    float* __restrict__ out, int Nrows)
{
    const int wave = threadIdx.x >> 6;
    const int lane = threadIdx.x & 63;
    const int r = blockIdx.x * 4 + wave;
    if (r >= Nrows) return;

    const int col = lane * 2;
    if (r == 0) {
        *(float2*)(out + col) = make_float2(0.f, 0.f);
        return;
    }
    const long n = r - 1;

    const float2 w1 = *(const float2*)(W + col);        // W[0:128] slice
    const float2 w2 = *(const float2*)(W + KD + col);   // W[128:256] slice

    // lane k (k<30) holds this node's k-th neighbor index
    int idxl = (lane < KK) ? scope[n * KK + lane] : 0;

    float  ek[KK];     // edge score (or -FLT_MAX for padding)
    float2 zr[KK];     // this lane's zo slice per neighbor

    #pragma unroll
    for (int k = 0; k < KK; ++k) {
        const int ik = __shfl(idxl, k, 64);             // wave-uniform
        const bool valid = (ik > 0);
        // branchless: padding reads row 0 (L1-hot), masked out below
        const long p = valid ? (long)(ik - 1) * KD : 0;
        const float2 a = *(const float2*)(zf + p + col);
        const float2 b = *(const float2*)(zo + p + col);
        zr[k] = b;
        float s = a.x * w1.x + a.y * w1.y + b.x * w2.x + b.y * w2.y;
        #pragma unroll
        for (int off = 32; off; off >>= 1)
            s += __shfl_xor(s, off, 64);
        // stable softplus; -FLT_MAX marks padding (matches ref mask eg != 0)
        const float sp = fmaxf(s, 0.f) + log1pf(expf(-fabsf(s)));
        ek[k] = valid ? sp : -FLT_MAX;
    }

    // masked softmax over the 30 registers (redundant per lane, no shuffles)
    float m = ek[0];
    #pragma unroll
    for (int k = 1; k < KK; ++k) m = fmaxf(m, ek[k]);

    float denom = 0.f;
    float pk[KK];
    #pragma unroll
    for (int k = 0; k < KK; ++k) {
        pk[k] = expf(ek[k] - m);     // padding: exp(-inf) = 0
        denom += pk[k];
    }
    const float inv = 1.f / denom;   // denom >= 1 (max term contributes 1)

    float2 acc = make_float2(0.f, 0.f);
    #pragma unroll
    for (int k = 0; k < KK; ++k) {
        acc.x += pk[k] * zr[k].x;    // padding: 0 * finite(row 0) = 0
        acc.y += pk[k] * zr[k].y;
    }
    *(float2*)(out + (long)r * KD + col) = make_float2(acc.x * inv, acc.y * inv);
}

extern "C" void kernel_launch(void* const* d_in, const int* in_sizes, int n_in,
                              void* d_out, int out_size, void* d_ws, size_t ws_size,
                              hipStream_t stream) {
    const float* zf    = (const float*)d_in[0];   // [P, D]
    const float* zo    = (const float*)d_in[1];   // [P, D]
    const int*   scope = (const int*)d_in[2];     // [N, K]
    const float* W     = (const float*)d_in[3];   // [2D, 1]
    float* out = (float*)d_out;                   // [(N+1), D]

    const int N = in_sizes[2] / KK;
    const int nrows = N + 1;
    const int grid = (nrows + 3) / 4;             // 4 rows (waves) per block
    fused_gat_kernel<<<grid, 256, 0, stream>>>(zf, zo, scope, W, out, nrows);
}

// Round 3
// 123.447 us; speedup vs baseline: 1.5792x; 1.5792x over previous
//
#include <hip/hip_runtime.h>
#include <float.h>
#include <math.h>

#define KP 500000
#define KN 25000
#define KK 30
#define KD 128

typedef float f32x4 __attribute__((ext_vector_type(4)));

// ---------------------------------------------------------------------------
// Kernel 0: mark referenced pairs. scope entries are 1-based; 0 = padding.
// Racy byte stores of 1 are benign and deterministic.
// ---------------------------------------------------------------------------
__global__ __launch_bounds__(256) void mark_kernel(
    const int* __restrict__ scope, unsigned char* __restrict__ flags, int total)
{
    int i = blockIdx.x * 256 + threadIdx.x;
    const int stride = gridDim.x * 256;
    for (; i < total; i += stride) {
        const int ik = scope[i];
        if (ik > 0) flags[ik - 1] = 1;
    }
}

// ---------------------------------------------------------------------------
// Kernel 1: e[p] = softplus( zf[p]·W[0:128] + zo[p]·W[128:256] )
// 32 lanes per pair, float4 loads. Skips pairs no node references.
// zf is loaded non-temporally (never reused); zo loads stay cached so the
// flagged zo rows (~138 MB) are L3-resident for the gather kernel.
// ---------------------------------------------------------------------------
__global__ __launch_bounds__(256) void edge_score_kernel(
    const float* __restrict__ zf, const float* __restrict__ zo,
    const float* __restrict__ W, const unsigned char* __restrict__ flags,
    float* __restrict__ e, int P)
{
    const int lane = threadIdx.x & 31;
    const float4 w1 = *(const float4*)(W + lane * 4);        // W[0:128]
    const float4 w2 = *(const float4*)(W + 128 + lane * 4);  // W[128:256]

    long pair = (long)blockIdx.x * 8 + (threadIdx.x >> 5);   // 8 pairs / block
    const long pstride = (long)gridDim.x * 8;

    for (; pair < P; pair += pstride) {
        if (flags && !flags[pair]) continue;   // unreferenced: never fetched
        const f32x4 a = __builtin_nontemporal_load(
            (const f32x4*)(zf + pair * KD + lane * 4));
        const float4 b = *(const float4*)(zo + pair * KD + lane * 4);
        float s = a.x * w1.x + a.y * w1.y + a.z * w1.z + a.w * w1.w
                + b.x * w2.x + b.y * w2.y + b.z * w2.z + b.w * w2.w;
        #pragma unroll
        for (int off = 16; off; off >>= 1)
            s += __shfl_xor(s, off, 32);
        if (lane == 0) {
            // numerically stable softplus = max(x,0) + log1p(exp(-|x|))
            e[pair] = fmaxf(s, 0.0f) + log1pf(expf(-fabsf(s)));
        }
    }
}

// ---------------------------------------------------------------------------
// Kernel 2: per output row r: r==0 -> zeros; else node n = r-1:
// masked softmax over <=30 gathered scores, then weighted gather of zo rows.
// One 64-lane wave per row; each lane owns a float2 column slice.
// ---------------------------------------------------------------------------
__global__ __launch_bounds__(256) void node_gather_kernel(
    const float* __restrict__ e, const float* __restrict__ zo,
    const int* __restrict__ scope, float* __restrict__ out, int Nrows)
{
    const int wave = threadIdx.x >> 6;
    const int lane = threadIdx.x & 63;
    const int r = blockIdx.x * 4 + wave;
    if (r >= Nrows) return;

    const int col = lane * 2;
    if (r == 0) {
        *(float2*)(out + col) = make_float2(0.f, 0.f);
        return;
    }
    const long n = r - 1;

    int   idx = 0;
    float ev  = 0.f;
    if (lane < KK) {
        idx = scope[n * KK + lane];
        if (idx > 0) ev = e[idx - 1];
    }

    const bool valid = (ev != 0.f);
    float logit = valid ? ev : -FLT_MAX;
    float m = logit;
    #pragma unroll
    for (int off = 32; off; off >>= 1)
        m = fmaxf(m, __shfl_xor(m, off, 64));

    float ex = valid ? expf(ev - m) : 0.f;
    float denom = ex;
    #pragma unroll
    for (int off = 32; off; off >>= 1)
        denom += __shfl_xor(denom, off, 64);
    denom = (denom > 0.f) ? denom : 1.f;
    const float alpha = ex / denom;

    float2 acc = make_float2(0.f, 0.f);
    #pragma unroll
    for (int k = 0; k < KK; ++k) {
        const int ik = __shfl(idx, k, 64);        // wave-uniform
        if (ik > 0) {
            const float ak = __shfl(alpha, k, 64);
            const float2 z = *(const float2*)(zo + (long)(ik - 1) * KD + col);
            acc.x += ak * z.x;
            acc.y += ak * z.y;
        }
    }
    *(float2*)(out + (long)r * KD + col) = acc;
}

extern "C" void kernel_launch(void* const* d_in, const int* in_sizes, int n_in,
                              void* d_out, int out_size, void* d_ws, size_t ws_size,
                              hipStream_t stream) {
    const float* zf    = (const float*)d_in[0];   // [P, D]
    const float* zo    = (const float*)d_in[1];   // [P, D]
    const int*   scope = (const int*)d_in[2];     // [N, K]
    const float* W     = (const float*)d_in[3];   // [2D, 1]
    float* out = (float*)d_out;                   // [(N+1), D]

    const int P = in_sizes[0] / KD;
    const int N = in_sizes[2] / KK;

    float* e = (float*)d_ws;                              // P floats
    unsigned char* flags = nullptr;                       // P bytes after e
    if (ws_size >= (size_t)P * sizeof(float) + (size_t)P) {
        flags = (unsigned char*)d_ws + (size_t)P * sizeof(float);
        hipMemsetAsync(flags, 0, (size_t)P, stream);
        mark_kernel<<<512, 256, 0, stream>>>(scope, flags, N * KK);
    }

    {
        const int grid = (P + 7) / 8;
        edge_score_kernel<<<grid, 256, 0, stream>>>(zf, zo, W, flags, e, P);
    }
    {
        const int nrows = N + 1;
        const int grid = (nrows + 3) / 4;
        node_gather_kernel<<<grid, 256, 0, stream>>>(e, zo, scope, out, nrows);
    }
}